// Round 4
// baseline (278.384 us; speedup 1.0000x reference)
//
#include <hip/hip_runtime.h>

using short8  = __attribute__((ext_vector_type(8))) short;
using floatx4 = __attribute__((ext_vector_type(4))) float;

#define NB   8192
#define DIN  256
#define DE   128
#define NEX  16384
#define ND   64
#define ESPLIT 16
#define EPB  (NEX/ESPLIT)   // 1024 exemplars per block
#define TE   64
#define NTIL (EPB/TE)       // 16 tiles
#define GAMMA_N 3.6787944117144233e-06f  // exp(-1)/100000

__device__ __forceinline__ unsigned short f2bf(float f) {
  unsigned int u = __float_as_uint(f);
  u += 0x7fffu + ((u >> 16) & 1u);
  return (unsigned short)(u >> 16);
}
__device__ __forceinline__ float bf2f(unsigned short h) {
  return __uint_as_float(((unsigned int)h) << 16);
}

__device__ __forceinline__ void gload_lds16(const void* g, void* l) {
  __builtin_amdgcn_global_load_lds(
      (const __attribute__((address_space(1))) void*)g,
      (__attribute__((address_space(3))) void*)l, 16, 0, 0);
}

__device__ __forceinline__ floatx4 mfma_bf16(short8 a, short8 b, floatx4 c) {
  return __builtin_amdgcn_mfma_f32_16x16x32_bf16(a, b, c, 0, 0, 0);
}

// ---------------- encoder: phi = x@W + b, store bf16 + |phi_bf|^2 ---------
__global__ __launch_bounds__(256) void k_encoder(
    const float* __restrict__ x, const float* __restrict__ W,
    const float* __restrict__ bias, unsigned short* __restrict__ phi_bf,
    float* __restrict__ pn)
{
  __shared__ float xs[32 * DIN];      // 32 KB
  __shared__ float part[32][2];
  const int rb  = blockIdx.x * 32;
  const int tid = threadIdx.x;
  for (int i = tid; i < 32 * DIN; i += 256) xs[i] = x[rb * DIN + i];
  __syncthreads();
  const int j  = tid & 127;
  const int rh = tid >> 7;            // 0/1 -> rows rh*16 ..
  const float bj = bias[j];
  float acc[16];
  #pragma unroll
  for (int r = 0; r < 16; ++r) acc[r] = bj;
  for (int k = 0; k < DIN; ++k) {
    const float wv = W[k * DE + j];
    #pragma unroll
    for (int r = 0; r < 16; ++r)
      acc[r] = fmaf(xs[(rh * 16 + r) * DIN + k], wv, acc[r]);
  }
  const int lane = tid & 63;
  const int jh   = (tid >> 6) & 1;
  #pragma unroll
  for (int r = 0; r < 16; ++r) {
    const int row = rh * 16 + r;
    const unsigned short hb = f2bf(acc[r]);
    phi_bf[(rb + row) * DE + j] = hb;
    const float hf = bf2f(hb);
    float sq = hf * hf;
    #pragma unroll
    for (int off = 1; off < 64; off <<= 1) sq += __shfl_xor(sq, off, 64);
    if (lane == 0) part[row][jh] = sq;
  }
  __syncthreads();
  if (tid < 32) pn[rb + tid] = part[tid][0] + part[tid][1];
}

// ---------------- exemplar prep: bf16 copy + |E_bf|^2 ---------------------
__global__ __launch_bounds__(128) void k_prep_e(
    const float* __restrict__ E, unsigned short* __restrict__ E_bf,
    float* __restrict__ en)
{
  __shared__ float part[2];
  const int e = blockIdx.x;
  const int j = threadIdx.x;
  const unsigned short hb = f2bf(E[e * DE + j]);
  E_bf[e * DE + j] = hb;
  const float hf = bf2f(hb);
  float sq = hf * hf;
  #pragma unroll
  for (int off = 1; off < 64; off <<= 1) sq += __shfl_xor(sq, off, 64);
  if ((j & 63) == 0) part[j >> 6] = sq;
  __syncthreads();
  if (j == 0) en[e] = part[0] + part[1];
}

// ---------------- KM curves -> transposed KM_t[t][e] bf16 -----------------
__global__ __launch_bounds__(256) void k_prep_km(
    const float* __restrict__ lev, const float* __restrict__ lcen,
    const float* __restrict__ lh, unsigned short* __restrict__ KM_t,
    float* __restrict__ baseKM)
{
  __shared__ unsigned short sm[64][65];
  const int tid = threadIdx.x;
  const int t   = tid & 63;
  const int wv  = tid >> 6;
  for (int ee = 0; ee < 16; ++ee) {
    const int el = wv * 16 + ee;
    const int e  = blockIdx.x * 64 + el;
    const float ev = __expf(lev[e * ND + t]);
    const float cn = __expf(lcen[e * ND + t]);
    float s = ev + cn;
    #pragma unroll
    for (int off = 1; off < 64; off <<= 1) {         // inclusive suffix sum
      const float o = __shfl(s, (t + off) & 63, 64);
      s += (t + off < 64) ? o : 0.0f;
    }
    const float haz = (s > 0.0f) ? (ev / s) : 0.0f;
    float lc = __logf(1.0f - haz + 1e-7f);
    #pragma unroll
    for (int off = 1; off < 64; off <<= 1) {         // inclusive prefix sum
      const float o = __shfl(lc, (t - off) & 63, 64);
      lc += (t >= off) ? o : 0.0f;
    }
    sm[el][t] = f2bf(__expf(lc));
  }
  __syncthreads();
  const int t_out = tid >> 2, prt = tid & 3;
  unsigned short tmp[16];
  #pragma unroll
  for (int i = 0; i < 16; ++i) tmp[i] = sm[prt * 16 + i][t_out];
  *reinterpret_cast<short8*>(KM_t + (size_t)t_out * NEX + blockIdx.x * 64 + prt * 16) =
      *reinterpret_cast<short8*>(&tmp[0]);
  *reinterpret_cast<short8*>(KM_t + (size_t)t_out * NEX + blockIdx.x * 64 + prt * 16 + 8) =
      *reinterpret_cast<short8*>(&tmp[8]);
  if (blockIdx.x == 0 && tid < 64) {
    const float h = 1.0f / (1.0f + __expf(-lh[t]));
    float l2 = __logf(1.0f - h + 1e-7f);
    #pragma unroll
    for (int off = 1; off < 64; off <<= 1) {
      const float o = __shfl(l2, (t - off) & 63, 64);
      l2 += (t >= off) ? o : 0.0f;
    }
    baseKM[t] = __expf(l2);
  }
}

// ---------------- fused (swapped operands): -------------------------------
// GEMM1': C1[e][r] = E . phi^T  -> kw packed to LDS (b64 writes)
// GEMM2': C2[t][r] = KM^T . kw^T -> accumulate in regs, atomic at end
__global__ __launch_bounds__(256, 4) void k_fused(
    const unsigned short* __restrict__ phi_bf, const float* __restrict__ pn,
    const unsigned short* __restrict__ E_bf, const float* __restrict__ en,
    const unsigned short* __restrict__ KM_t,
    float* __restrict__ numer_acc, float* __restrict__ denom_acc)
{
  __shared__ __align__(16) unsigned char E_lds[16384];   // [64 e][256B], swizzled
  __shared__ __align__(16) unsigned char KM_lds[8192];   // [64 t][128B], swizzled
  __shared__ __align__(16) unsigned char kw_lds[16384];  // per-wave [32 r][128B], swizzled

  const int tid = threadIdx.x;
  const int w   = tid >> 6;
  const int l   = tid & 63;
  const int lr  = l & 15;
  const int g   = l >> 4;
  const int rowbase = blockIdx.y * 128 + w * 32;
  const int ebase0  = blockIdx.x * EPB;
  const int swz = (lr & 7) << 4;

  // persistent B-fragments: phi rows (cols of C), loaded once
  short8 phiB[2][4];
  float  pnf[2];
  #pragma unroll
  for (int n = 0; n < 2; ++n) {
    const int r = rowbase + n * 16 + lr;
    #pragma unroll
    for (int kq = 0; kq < 4; ++kq)
      phiB[n][kq] = *reinterpret_cast<const short8*>(phi_bf + r * DE + kq * 32 + g * 8);
    pnf[n] = pn[r];
  }

  floatx4 c2[4][2];
  #pragma unroll
  for (int m2 = 0; m2 < 4; ++m2)
    #pragma unroll
    for (int n = 0; n < 2; ++n) c2[m2][n] = (floatx4){0.f, 0.f, 0.f, 0.f};
  float dn[2] = {0.f, 0.f};

  for (int it = 0; it < NTIL; ++it) {
    const int ebase = ebase0 + it * TE;
    __syncthreads();                   // prev tile's LDS readers done
    // stage E tile: 16 x 1KB chunks, linear LDS dest, pre-swizzled source
    #pragma unroll
    for (int i = 0; i < 4; ++i) {
      const int c    = w * 4 + i;
      const int row  = c * 4 + (l >> 4);
      const int colB = (l & 15) * 16;
      gload_lds16((const char*)E_bf + (size_t)(ebase + row) * 256 +
                      (colB ^ ((row & 7) << 4)),
                  &E_lds[c * 1024]);
    }
    // stage KM tile: 8 x 1KB chunks from transposed KM_t
    #pragma unroll
    for (int i = 0; i < 2; ++i) {
      const int c    = w * 2 + i;
      const int trow = c * 8 + (l >> 3);
      const int colB = (l & 7) * 16;
      gload_lds16((const char*)KM_t + (size_t)trow * (NEX * 2) + ebase * 2 +
                      (colB ^ ((trow & 7) << 4)),
                  &KM_lds[c * 1024]);
    }
    __syncthreads();                   // vmcnt(0) drained by compiler before barrier

    // GEMM1' + kw elementwise + pack to kw_lds
    #pragma unroll
    for (int m = 0; m < 4; ++m) {
      short8 ea[4];
      #pragma unroll
      for (int kq = 0; kq < 4; ++kq)
        ea[kq] = *reinterpret_cast<const short8*>(
            &E_lds[(m * 16 + lr) * 256 + ((kq * 64 + g * 16) ^ swz)]);
      floatx4 c1[2];
      c1[0] = (floatx4){0.f, 0.f, 0.f, 0.f};
      c1[1] = (floatx4){0.f, 0.f, 0.f, 0.f};
      #pragma unroll
      for (int kq = 0; kq < 4; ++kq) {
        c1[0] = mfma_bf16(ea[kq], phiB[0][kq], c1[0]);
        c1[1] = mfma_bf16(ea[kq], phiB[1][kq], c1[1]);
      }
      const floatx4 en4 = *reinterpret_cast<const floatx4*>(&en[ebase + m * 16 + g * 4]);
      #pragma unroll
      for (int n = 0; n < 2; ++n) {
        float kwv[4];
        #pragma unroll
        for (int rg = 0; rg < 4; ++rg) {
          float d2 = en4[rg] + pnf[n] - 2.0f * c1[n][rg];
          d2 = fmaxf(d2, 0.0f);
          kwv[rg] = (d2 <= 1.0f) ? __expf(-d2) : 0.0f;
          dn[n] += kwv[rg];
        }
        unsigned int pk0, pk1;
        asm("v_cvt_pk_bf16_f32 %0, %1, %2" : "=v"(pk0) : "v"(kwv[0]), "v"(kwv[1]));
        asm("v_cvt_pk_bf16_f32 %0, %1, %2" : "=v"(pk1) : "v"(kwv[2]), "v"(kwv[3]));
        const unsigned long long pk = (unsigned long long)pk0 |
                                      ((unsigned long long)pk1 << 32);
        *reinterpret_cast<unsigned long long*>(
            &kw_lds[w * 4096 + (n * 16 + lr) * 128 + ((m * 32 + g * 8) ^ swz)]) = pk;
      }
    }

    // GEMM2': same-wave LDS RAW (in-order DS pipe), no barrier needed
    #pragma unroll
    for (int ks = 0; ks < 2; ++ks) {
      short8 kwB[2];
      #pragma unroll
      for (int n = 0; n < 2; ++n)
        kwB[n] = *reinterpret_cast<const short8*>(
            &kw_lds[w * 4096 + (n * 16 + lr) * 128 + ((ks * 64 + g * 16) ^ swz)]);
      #pragma unroll
      for (int m2 = 0; m2 < 4; ++m2) {
        const short8 kma = *reinterpret_cast<const short8*>(
            &KM_lds[(m2 * 16 + lr) * 128 + ((ks * 64 + g * 16) ^ swz)]);
        c2[m2][0] = mfma_bf16(kma, kwB[0], c2[m2][0]);
        c2[m2][1] = mfma_bf16(kma, kwB[1], c2[m2][1]);
      }
    }
  }

  // epilogue: denom (lane-local, reduce over g) + numer atomics
  #pragma unroll
  for (int n = 0; n < 2; ++n) {
    float v = dn[n];
    v += __shfl_xor(v, 16, 64);
    v += __shfl_xor(v, 32, 64);
    if (l < 16) atomicAdd(&denom_acc[rowbase + n * 16 + lr], v);
  }
  #pragma unroll
  for (int m2 = 0; m2 < 4; ++m2)
    #pragma unroll
    for (int n = 0; n < 2; ++n)
      #pragma unroll
      for (int rg = 0; rg < 4; ++rg)
        atomicAdd(&numer_acc[(size_t)(rowbase + n * 16 + lr) * ND + m2 * 16 + g * 4 + rg],
                  c2[m2][n][rg]);
}

// ---------------- finalize ------------------------------------------------
__global__ __launch_bounds__(256) void k_finalize(
    const float* __restrict__ numer_acc, const float* __restrict__ denom_acc,
    const float* __restrict__ baseKM, float* __restrict__ out)
{
  const int idx = blockIdx.x * 256 + threadIdx.x;
  const int b = idx >> 6;
  const int t = idx & 63;
  const float num = numer_acc[idx] + GAMMA_N * baseKM[t];
  const float den = denom_acc[b] + GAMMA_N + 1e-12f;
  float r = num / den;
  r = fminf(fmaxf(r, 1e-12f), 1.0f - 1e-12f);
  out[idx] = r;
}

extern "C" void kernel_launch(void* const* d_in, const int* in_sizes, int n_in,
                              void* d_out, int out_size, void* d_ws, size_t ws_size,
                              hipStream_t stream)
{
  const float* x    = (const float*)d_in[0];
  const float* W    = (const float*)d_in[1];
  const float* bias = (const float*)d_in[2];
  const float* E    = (const float*)d_in[3];
  const float* lev  = (const float*)d_in[4];
  const float* lcen = (const float*)d_in[5];
  const float* lh   = (const float*)d_in[6];
  float* out = (float*)d_out;

  char* ws = (char*)d_ws;
  size_t off = 0;
  auto alloc = [&](size_t bytes) -> void* {
    void* p = ws + off;
    off += (bytes + 255) & ~(size_t)255;
    return p;
  };
  unsigned short* phi_bf = (unsigned short*)alloc((size_t)NB * DE * 2);
  unsigned short* E_bf   = (unsigned short*)alloc((size_t)NEX * DE * 2);
  unsigned short* KM_t   = (unsigned short*)alloc((size_t)ND * NEX * 2);
  float* pn        = (float*)alloc((size_t)NB * 4);
  float* en        = (float*)alloc((size_t)NEX * 4);
  float* baseKM    = (float*)alloc((size_t)ND * 4);
  float* numer_acc = (float*)alloc((size_t)NB * ND * 4);
  float* denom_acc = (float*)alloc((size_t)NB * 4);

  hipMemsetAsync(numer_acc, 0, (size_t)NB * ND * 4, stream);
  hipMemsetAsync(denom_acc, 0, (size_t)NB * 4, stream);

  k_encoder<<<NB / 32, 256, 0, stream>>>(x, W, bias, phi_bf, pn);
  k_prep_e<<<NEX, 128, 0, stream>>>(E, E_bf, en);
  k_prep_km<<<NEX / 64, 256, 0, stream>>>(lev, lcen, lh, KM_t, baseKM);
  k_fused<<<dim3(ESPLIT, NB / 128), 256, 0, stream>>>(phi_bf, pn, E_bf, en, KM_t,
                                                      numer_acc, denom_acc);
  k_finalize<<<(NB * ND) / 256, 256, 0, stream>>>(numer_acc, denom_acc, baseKM, out);
}

// Round 5
// 201.325 us; speedup vs baseline: 1.3828x; 1.3828x over previous
//
#include <hip/hip_runtime.h>

using short8  = __attribute__((ext_vector_type(8))) short;
using floatx4 = __attribute__((ext_vector_type(4))) float;

#define NB   8192
#define DIN  256
#define DE   128
#define NEX  16384
#define ND   64
#define ESPLIT 16
#define EPB  (NEX/ESPLIT)   // 1024 exemplars per block
#define TE   64
#define NTIL (EPB/TE)       // 16 tiles
#define GAMMA_N 3.6787944117144233e-06f  // exp(-1)/100000

__device__ __forceinline__ unsigned short f2bf(float f) {
  unsigned int u = __float_as_uint(f);
  u += 0x7fffu + ((u >> 16) & 1u);
  return (unsigned short)(u >> 16);
}
__device__ __forceinline__ float bf2f(unsigned short h) {
  return __uint_as_float(((unsigned int)h) << 16);
}

__device__ __forceinline__ void gload_lds16(const void* g, void* l) {
  __builtin_amdgcn_global_load_lds(
      (const __attribute__((address_space(1))) void*)g,
      (__attribute__((address_space(3))) void*)l, 16, 0, 0);
}

__device__ __forceinline__ floatx4 mfma_bf16(short8 a, short8 b, floatx4 c) {
  return __builtin_amdgcn_mfma_f32_16x16x32_bf16(a, b, c, 0, 0, 0);
}

// ---------------- encoder: phi = x@W + b, store bf16 + |phi_bf|^2 ---------
__global__ __launch_bounds__(256) void k_encoder(
    const float* __restrict__ x, const float* __restrict__ W,
    const float* __restrict__ bias, unsigned short* __restrict__ phi_bf,
    float* __restrict__ pn)
{
  __shared__ float xs[32 * DIN];      // 32 KB
  __shared__ float part[32][2];
  const int rb  = blockIdx.x * 32;
  const int tid = threadIdx.x;
  for (int i = tid; i < 32 * DIN; i += 256) xs[i] = x[rb * DIN + i];
  __syncthreads();
  const int j  = tid & 127;
  const int rh = tid >> 7;            // 0/1 -> rows rh*16 ..
  const float bj = bias[j];
  float acc[16];
  #pragma unroll
  for (int r = 0; r < 16; ++r) acc[r] = bj;
  for (int k = 0; k < DIN; ++k) {
    const float wv = W[k * DE + j];
    #pragma unroll
    for (int r = 0; r < 16; ++r)
      acc[r] = fmaf(xs[(rh * 16 + r) * DIN + k], wv, acc[r]);
  }
  const int lane = tid & 63;
  const int jh   = (tid >> 6) & 1;
  #pragma unroll
  for (int r = 0; r < 16; ++r) {
    const int row = rh * 16 + r;
    const unsigned short hb = f2bf(acc[r]);
    phi_bf[(rb + row) * DE + j] = hb;
    const float hf = bf2f(hb);
    float sq = hf * hf;
    #pragma unroll
    for (int off = 1; off < 64; off <<= 1) sq += __shfl_xor(sq, off, 64);
    if (lane == 0) part[row][jh] = sq;
  }
  __syncthreads();
  if (tid < 32) pn[rb + tid] = part[tid][0] + part[tid][1];
}

// ---------------- exemplar prep: bf16 copy + |E_bf|^2 ---------------------
__global__ __launch_bounds__(128) void k_prep_e(
    const float* __restrict__ E, unsigned short* __restrict__ E_bf,
    float* __restrict__ en)
{
  __shared__ float part[2];
  const int e = blockIdx.x;
  const int j = threadIdx.x;
  const unsigned short hb = f2bf(E[e * DE + j]);
  E_bf[e * DE + j] = hb;
  const float hf = bf2f(hb);
  float sq = hf * hf;
  #pragma unroll
  for (int off = 1; off < 64; off <<= 1) sq += __shfl_xor(sq, off, 64);
  if ((j & 63) == 0) part[j >> 6] = sq;
  __syncthreads();
  if (j == 0) en[e] = part[0] + part[1];
}

// ---------------- KM curves -> transposed KM_t[t][e] bf16 -----------------
__global__ __launch_bounds__(256) void k_prep_km(
    const float* __restrict__ lev, const float* __restrict__ lcen,
    const float* __restrict__ lh, unsigned short* __restrict__ KM_t,
    float* __restrict__ baseKM)
{
  __shared__ unsigned short sm[64][65];
  const int tid = threadIdx.x;
  const int t   = tid & 63;
  const int wv  = tid >> 6;
  for (int ee = 0; ee < 16; ++ee) {
    const int el = wv * 16 + ee;
    const int e  = blockIdx.x * 64 + el;
    const float ev = __expf(lev[e * ND + t]);
    const float cn = __expf(lcen[e * ND + t]);
    float s = ev + cn;
    #pragma unroll
    for (int off = 1; off < 64; off <<= 1) {         // inclusive suffix sum
      const float o = __shfl(s, (t + off) & 63, 64);
      s += (t + off < 64) ? o : 0.0f;
    }
    const float haz = (s > 0.0f) ? (ev / s) : 0.0f;
    float lc = __logf(1.0f - haz + 1e-7f);
    #pragma unroll
    for (int off = 1; off < 64; off <<= 1) {         // inclusive prefix sum
      const float o = __shfl(lc, (t - off) & 63, 64);
      lc += (t >= off) ? o : 0.0f;
    }
    sm[el][t] = f2bf(__expf(lc));
  }
  __syncthreads();
  const int t_out = tid >> 2, prt = tid & 3;
  unsigned short tmp[16];
  #pragma unroll
  for (int i = 0; i < 16; ++i) tmp[i] = sm[prt * 16 + i][t_out];
  *reinterpret_cast<short8*>(KM_t + (size_t)t_out * NEX + blockIdx.x * 64 + prt * 16) =
      *reinterpret_cast<short8*>(&tmp[0]);
  *reinterpret_cast<short8*>(KM_t + (size_t)t_out * NEX + blockIdx.x * 64 + prt * 16 + 8) =
      *reinterpret_cast<short8*>(&tmp[8]);
  if (blockIdx.x == 0 && tid < 64) {
    const float h = 1.0f / (1.0f + __expf(-lh[t]));
    float l2 = __logf(1.0f - h + 1e-7f);
    #pragma unroll
    for (int off = 1; off < 64; off <<= 1) {
      const float o = __shfl(l2, (t - off) & 63, 64);
      l2 += (t >= off) ? o : 0.0f;
    }
    baseKM[t] = __expf(l2);
  }
}

// ---------------- fused (swapped operands): -------------------------------
// GEMM1': C1[e][r] = E . phi^T  -> kw packed to LDS (b64 writes)
// GEMM2': C2[t][r] = KM^T . kw^T -> regs; epilogue = PLAIN partial stores
__global__ __launch_bounds__(256, 4) void k_fused(
    const unsigned short* __restrict__ phi_bf, const float* __restrict__ pn,
    const unsigned short* __restrict__ E_bf, const float* __restrict__ en,
    const unsigned short* __restrict__ KM_t,
    float* __restrict__ numer_p, float* __restrict__ denom_p)
{
  __shared__ __align__(16) unsigned char E_lds[16384];   // [64 e][256B], swizzled
  __shared__ __align__(16) unsigned char KM_lds[8192];   // [64 t][128B], swizzled
  __shared__ __align__(16) unsigned char kw_lds[16384];  // per-wave [32 r][128B], swizzled

  const int tid = threadIdx.x;
  const int w   = tid >> 6;
  const int l   = tid & 63;
  const int lr  = l & 15;
  const int g   = l >> 4;
  const int rowbase = blockIdx.y * 128 + w * 32;
  const int ebase0  = blockIdx.x * EPB;
  const int swz = (lr & 7) << 4;

  // persistent B-fragments: phi rows (cols of C), loaded once
  short8 phiB[2][4];
  float  pnf[2];
  #pragma unroll
  for (int n = 0; n < 2; ++n) {
    const int r = rowbase + n * 16 + lr;
    #pragma unroll
    for (int kq = 0; kq < 4; ++kq)
      phiB[n][kq] = *reinterpret_cast<const short8*>(phi_bf + r * DE + kq * 32 + g * 8);
    pnf[n] = pn[r];
  }

  floatx4 c2[4][2];
  #pragma unroll
  for (int m2 = 0; m2 < 4; ++m2)
    #pragma unroll
    for (int n = 0; n < 2; ++n) c2[m2][n] = (floatx4){0.f, 0.f, 0.f, 0.f};
  float dn[2] = {0.f, 0.f};

  for (int it = 0; it < NTIL; ++it) {
    const int ebase = ebase0 + it * TE;
    __syncthreads();                   // prev tile's LDS readers done
    // stage E tile: 16 x 1KB chunks, linear LDS dest, pre-swizzled source
    #pragma unroll
    for (int i = 0; i < 4; ++i) {
      const int c    = w * 4 + i;
      const int row  = c * 4 + (l >> 4);
      const int colB = (l & 15) * 16;
      gload_lds16((const char*)E_bf + (size_t)(ebase + row) * 256 +
                      (colB ^ ((row & 7) << 4)),
                  &E_lds[c * 1024]);
    }
    // stage KM tile: 8 x 1KB chunks from transposed KM_t
    #pragma unroll
    for (int i = 0; i < 2; ++i) {
      const int c    = w * 2 + i;
      const int trow = c * 8 + (l >> 3);
      const int colB = (l & 7) * 16;
      gload_lds16((const char*)KM_t + (size_t)trow * (NEX * 2) + ebase * 2 +
                      (colB ^ ((trow & 7) << 4)),
                  &KM_lds[c * 1024]);
    }
    __syncthreads();                   // vmcnt(0) drained by compiler before barrier

    // GEMM1' + kw elementwise + pack to kw_lds
    #pragma unroll
    for (int m = 0; m < 4; ++m) {
      short8 ea[4];
      #pragma unroll
      for (int kq = 0; kq < 4; ++kq)
        ea[kq] = *reinterpret_cast<const short8*>(
            &E_lds[(m * 16 + lr) * 256 + ((kq * 64 + g * 16) ^ swz)]);
      floatx4 c1[2];
      c1[0] = (floatx4){0.f, 0.f, 0.f, 0.f};
      c1[1] = (floatx4){0.f, 0.f, 0.f, 0.f};
      #pragma unroll
      for (int kq = 0; kq < 4; ++kq) {
        c1[0] = mfma_bf16(ea[kq], phiB[0][kq], c1[0]);
        c1[1] = mfma_bf16(ea[kq], phiB[1][kq], c1[1]);
      }
      const floatx4 en4 = *reinterpret_cast<const floatx4*>(&en[ebase + m * 16 + g * 4]);
      #pragma unroll
      for (int n = 0; n < 2; ++n) {
        float kwv[4];
        #pragma unroll
        for (int rg = 0; rg < 4; ++rg) {
          float d2 = en4[rg] + pnf[n] - 2.0f * c1[n][rg];
          d2 = fmaxf(d2, 0.0f);
          kwv[rg] = (d2 <= 1.0f) ? __expf(-d2) : 0.0f;
          dn[n] += kwv[rg];
        }
        unsigned int pk0, pk1;
        asm("v_cvt_pk_bf16_f32 %0, %1, %2" : "=v"(pk0) : "v"(kwv[0]), "v"(kwv[1]));
        asm("v_cvt_pk_bf16_f32 %0, %1, %2" : "=v"(pk1) : "v"(kwv[2]), "v"(kwv[3]));
        const unsigned long long pk = (unsigned long long)pk0 |
                                      ((unsigned long long)pk1 << 32);
        *reinterpret_cast<unsigned long long*>(
            &kw_lds[w * 4096 + (n * 16 + lr) * 128 + ((m * 32 + g * 8) ^ swz)]) = pk;
      }
    }

    // GEMM2': same-wave LDS RAW (in-order DS pipe), no barrier needed
    #pragma unroll
    for (int ks = 0; ks < 2; ++ks) {
      short8 kwB[2];
      #pragma unroll
      for (int n = 0; n < 2; ++n)
        kwB[n] = *reinterpret_cast<const short8*>(
            &kw_lds[w * 4096 + (n * 16 + lr) * 128 + ((ks * 64 + g * 16) ^ swz)]);
      #pragma unroll
      for (int m2 = 0; m2 < 4; ++m2) {
        const short8 kma = *reinterpret_cast<const short8*>(
            &KM_lds[(m2 * 16 + lr) * 128 + ((ks * 64 + g * 16) ^ swz)]);
        c2[m2][0] = mfma_bf16(kma, kwB[0], c2[m2][0]);
        c2[m2][1] = mfma_bf16(kma, kwB[1], c2[m2][1]);
      }
    }
  }

  // epilogue: PLAIN stores of per-split partials (no atomics, no init needed)
  #pragma unroll
  for (int n = 0; n < 2; ++n) {
    float v = dn[n];
    v += __shfl_xor(v, 16, 64);
    v += __shfl_xor(v, 32, 64);
    if (l < 16) denom_p[(size_t)blockIdx.x * NB + rowbase + n * 16 + lr] = v;
  }
  float* np = numer_p + ((size_t)blockIdx.x * NB + rowbase) * ND;
  #pragma unroll
  for (int n = 0; n < 2; ++n)
    #pragma unroll
    for (int m2 = 0; m2 < 4; ++m2)
      *reinterpret_cast<floatx4*>(&np[(n * 16 + lr) * ND + m2 * 16 + g * 4]) =
          c2[m2][n];
}

// ---------------- finalize: reduce ESPLIT partials + clip -----------------
__global__ __launch_bounds__(256) void k_finalize(
    const float* __restrict__ numer_p, const float* __restrict__ denom_p,
    const float* __restrict__ baseKM, float* __restrict__ out)
{
  const int idx = blockIdx.x * 256 + threadIdx.x;
  const int b = idx >> 6;
  const int t = idx & 63;
  float num = 0.f, den = 0.f;
  #pragma unroll
  for (int s = 0; s < ESPLIT; ++s) {
    num += numer_p[(size_t)s * NB * ND + idx];
    den += denom_p[(size_t)s * NB + b];
  }
  num += GAMMA_N * baseKM[t];
  den += GAMMA_N + 1e-12f;
  float r = num / den;
  r = fminf(fmaxf(r, 1e-12f), 1.0f - 1e-12f);
  out[idx] = r;
}

extern "C" void kernel_launch(void* const* d_in, const int* in_sizes, int n_in,
                              void* d_out, int out_size, void* d_ws, size_t ws_size,
                              hipStream_t stream)
{
  const float* x    = (const float*)d_in[0];
  const float* W    = (const float*)d_in[1];
  const float* bias = (const float*)d_in[2];
  const float* E    = (const float*)d_in[3];
  const float* lev  = (const float*)d_in[4];
  const float* lcen = (const float*)d_in[5];
  const float* lh   = (const float*)d_in[6];
  float* out = (float*)d_out;

  char* ws = (char*)d_ws;
  size_t off = 0;
  auto alloc = [&](size_t bytes) -> void* {
    void* p = ws + off;
    off += (bytes + 255) & ~(size_t)255;
    return p;
  };
  unsigned short* phi_bf = (unsigned short*)alloc((size_t)NB * DE * 2);
  unsigned short* E_bf   = (unsigned short*)alloc((size_t)NEX * DE * 2);
  unsigned short* KM_t   = (unsigned short*)alloc((size_t)ND * NEX * 2);
  float* pn      = (float*)alloc((size_t)NB * 4);
  float* en      = (float*)alloc((size_t)NEX * 4);
  float* baseKM  = (float*)alloc((size_t)ND * 4);
  float* numer_p = (float*)alloc((size_t)ESPLIT * NB * ND * 4);  // 134 MB
  float* denom_p = (float*)alloc((size_t)ESPLIT * NB * 4);

  k_encoder<<<NB / 32, 256, 0, stream>>>(x, W, bias, phi_bf, pn);
  k_prep_e<<<NEX, 128, 0, stream>>>(E, E_bf, en);
  k_prep_km<<<NEX / 64, 256, 0, stream>>>(lev, lcen, lh, KM_t, baseKM);
  k_fused<<<dim3(ESPLIT, NB / 128), 256, 0, stream>>>(phi_bf, pn, E_bf, en, KM_t,
                                                      numer_p, denom_p);
  k_finalize<<<(NB * ND) / 256, 256, 0, stream>>>(numer_p, denom_p, baseKM, out);
}